// Round 13
// baseline (161.991 us; speedup 1.0000x reference)
//
#include <hip/hip_runtime.h>
#include <stdint.h>

// Problem constants
#define BB 16
#define CC 512
#define CQK 64
#define NN 1024   // H*W = 32*32

typedef __attribute__((ext_vector_type(8))) short bf16x8;
typedef __attribute__((ext_vector_type(4))) short short4v;
typedef __attribute__((ext_vector_type(4))) float f32x4;

static __device__ __forceinline__ unsigned short f2bf(float f) {
  uint32_t u = __float_as_uint(f);
  u += 0x7FFFu + ((u >> 16) & 1u);
  return (unsigned short)(u >> 16);
}

// Async global->LDS, 16B per lane. LDS dest = wave-uniform base + lane*16.
static __device__ __forceinline__ void gll16(const unsigned short* g, unsigned short* l) {
  const __attribute__((address_space(1))) unsigned int* gp =
      reinterpret_cast<const __attribute__((address_space(1))) unsigned int*>(
          reinterpret_cast<uintptr_t>(g));
  __attribute__((address_space(3))) unsigned int* lp =
      reinterpret_cast<__attribute__((address_space(3))) unsigned int*>(
          (unsigned int)reinterpret_cast<uintptr_t>(l));
  __builtin_amdgcn_global_load_lds(gp, lp, 16, 0, 0);
}

// ---------------------------------------------------------------------------
// Kernel 1: transpose x -> xT bf16 + weight pack (R8 body, unchanged).
// grid (N/64=16, C/64=8, B=16), block 256
// ---------------------------------------------------------------------------
__global__ __launch_bounds__(256) void k_prep(
    const float* __restrict__ x, unsigned short* __restrict__ xT,
    const float* __restrict__ Wq, const float* __restrict__ Wk,
    const float* __restrict__ Wv, unsigned short* __restrict__ Wall) {
  __shared__ float tile[64][65];  // 16.6 KB
  int b = blockIdx.z;
  int c0 = blockIdx.y * 64;
  int n0 = blockIdx.x * 64;
  int t = threadIdx.x;

  int flat = ((int)blockIdx.z * gridDim.y + blockIdx.y) * gridDim.x + blockIdx.x;
  if (flat < 320) {
    int e = (flat * 256 + t) * 4;
    int o = e >> 9;
    int c = e & 511;
    const float* src;
    if (o < 64)        src = Wq + (size_t)o * 512;
    else if (o < 128)  src = Wk + (size_t)(o - 64) * 512;
    else               src = Wv + (size_t)(o - 128) * 512;
    float4 v = *(const float4*)(src + c);
    short4v pk;
    pk[0] = (short)f2bf(v.x); pk[1] = (short)f2bf(v.y);
    pk[2] = (short)f2bf(v.z); pk[3] = (short)f2bf(v.w);
    *(short4v*)(Wall + e) = pk;
  }

  int r = t >> 2;        // 0..63 : c-row within tile
  int cg = t & 3;        // 0..3  : 16-float column group
  const float* xp = x + ((size_t)(b * CC + c0 + r)) * NN + n0;
#pragma unroll
  for (int k = 0; k < 4; k++) {
    float4 v = *(const float4*)(xp + k * 16 + cg * 4);
    int cb = k * 16 + cg * 4;
    tile[r][cb + 0] = v.x;
    tile[r][cb + 1] = v.y;
    tile[r][cb + 2] = v.z;
    tile[r][cb + 3] = v.w;
  }
  __syncthreads();

  int n = t >> 2;        // 0..63 : n-row of output
  unsigned short* xq = xT + ((size_t)(b * NN + n0 + n)) * CC + c0 + cg * 16;
  short4v p[4];
#pragma unroll
  for (int q = 0; q < 4; q++) {
#pragma unroll
    for (int j = 0; j < 4; j++) p[q][j] = (short)f2bf(tile[cg * 16 + q * 4 + j][n]);
  }
  *(short4v*)(xq + 0) = p[0];
  *(short4v*)(xq + 4) = p[1];
  *(short4v*)(xq + 8) = p[2];
  *(short4v*)(xq + 12) = p[3];
}

// ---------------------------------------------------------------------------
// Kernel 2: GEMM1 (R12 body: counted-vmcnt dbuf, Q->Qb / K->Kp split).
//   THIS ROUND: vbuf epilogue coalesced — acc fragments go through a
//   [64][136] bf16 LDS tile (aliased over the dead ldsA/ldsB, 2 passes of
//   64 c-rows) and stream out as 16B bf16x8 stores (was: 64 scalar 2B
//   stores/thread in 32B segments at 2KB stride — the write-side scatter).
// ---------------------------------------------------------------------------
__global__ __launch_bounds__(256) void k_gemm1(
    const unsigned short* __restrict__ Wall, const unsigned short* __restrict__ xT,
    const float* __restrict__ bq, const float* __restrict__ bk,
    const float* __restrict__ bv,
    unsigned short* __restrict__ Qb, unsigned short* __restrict__ Kp,
    unsigned short* __restrict__ vbuf) {
  __shared__ __align__(16) unsigned short smem[16384];  // 32 KB
  unsigned short* ldsA = smem;          // 2 x 4096 ushorts
  unsigned short* ldsB = smem + 8192;   // 2 x 4096 ushorts
  int bid = blockIdx.x;
  int swz = (bid & 7) * 80 + (bid >> 3);
  int nx = swz & 7;
  int rest = swz >> 3;
  int oy = rest % 5;
  int b = rest / 5;
  int o0 = oy * 128;
  int n0 = nx * 128;
  int t = threadIdx.x;
  int w = t >> 6, l = t & 63;
  int wm = w & 1, wn = w >> 1;
  int lr = l & 15, lq = l >> 4;

  f32x4 acc[4][4];
#pragma unroll
  for (int i = 0; i < 4; i++)
#pragma unroll
    for (int j = 0; j < 4; j++) acc[i][j] = (f32x4){0.f, 0.f, 0.f, 0.f};

  const unsigned short* Ab = Wall + (size_t)o0 * CC;
  const unsigned short* Bb = xT + ((size_t)b * NN + n0) * CC;
  int srow = t >> 2;
  int skq = (t & 3) * 8;
  int ldsw = (t >> 6) * 512;

#pragma unroll
  for (int p = 0; p < 2; p++) {
    int r = p * 64 + srow;
    gll16(&Ab[(size_t)r * CC + skq], &ldsA[p * 2048 + ldsw]);
    gll16(&Bb[(size_t)r * CC + skq], &ldsB[p * 2048 + ldsw]);
  }

  for (int s = 0; s < 16; ++s) {
    int cur = s & 1;
    if (s < 15) {
      int kt = (s + 1) * 32;
#pragma unroll
      for (int p = 0; p < 2; p++) {
        int r = p * 64 + srow;
        gll16(&Ab[(size_t)r * CC + kt + skq], &ldsA[(cur ^ 1) * 4096 + p * 2048 + ldsw]);
        gll16(&Bb[(size_t)r * CC + kt + skq], &ldsB[(cur ^ 1) * 4096 + p * 2048 + ldsw]);
      }
    }
    __builtin_amdgcn_sched_barrier(0);
    if (s < 15) {
      asm volatile("s_waitcnt vmcnt(4)" ::: "memory");
    } else {
      asm volatile("s_waitcnt vmcnt(0)" ::: "memory");
    }
    __builtin_amdgcn_sched_barrier(0);
    __builtin_amdgcn_s_barrier();

    bf16x8 af[4], bfr[4];
#pragma unroll
    for (int i = 0; i < 4; i++)
      af[i] = *(const bf16x8*)(&ldsA[cur * 4096 + (wm * 64 + i * 16 + lr) * 32 + lq * 8]);
#pragma unroll
    for (int j = 0; j < 4; j++)
      bfr[j] = *(const bf16x8*)(&ldsB[cur * 4096 + (wn * 64 + j * 16 + lr) * 32 + lq * 8]);
#pragma unroll
    for (int i = 0; i < 4; i++)
#pragma unroll
      for (int j = 0; j < 4; j++)
        acc[i][j] = __builtin_amdgcn_mfma_f32_16x16x32_bf16(af[i], bfr[j], acc[i][j], 0, 0, 0);

    __builtin_amdgcn_s_barrier();
  }

  if (o0 == 0) {
    if (wm == 0) {
      // ---- Q half -> Qb[b][n][64] (unchanged)
#pragma unroll
      for (int i = 0; i < 4; i++) {
        int ob = i * 16 + lq * 4;
#pragma unroll
        for (int j = 0; j < 4; j++) {
          int n = n0 + wn * 64 + j * 16 + lr;
          short4v pk;
#pragma unroll
          for (int r = 0; r < 4; r++) pk[r] = (short)f2bf(acc[i][j][r] + bq[ob + r]);
          *(short4v*)(&Qb[((size_t)b * NN + n) * 64 + ob]) = pk;
        }
      }
    } else {
      // ---- K half -> Kp permuted (unchanged)
#pragma unroll
      for (int i = 0; i < 4; i++) {
#pragma unroll
        for (int j = 0; j < 4; j++) {
          int n = n0 + wn * 64 + j * 16 + lr;
          short4v pk;
#pragma unroll
          for (int r = 0; r < 4; r++) pk[r] = (short)f2bf(acc[i][j][r] + bk[i * 16 + lq * 4 + r]);
          size_t idx = (size_t)b * 65536 + (size_t)(n >> 4) * 1024 +
                       (size_t)(i * 2 + (lq >> 1)) * 128 + (n & 15) * 8 + (lq & 1) * 4;
          *(short4v*)(&Kp[idx]) = pk;
        }
      }
    }
  } else {
    // ---- V: coalesced epilogue via [64][136] LDS tile, 2 passes ----
    int cb = o0 - 128;
    unsigned short* tl = smem;  // 64*136 = 8704 ushorts (17.4 KB), ldsA/B dead
#pragma unroll
    for (int p = 0; p < 2; p++) {
      __syncthreads();  // p=0: after final K-loop barrier (safe); p=1: WAR vs pass-0 reads
      if (wm == p) {
#pragma unroll
        for (int i = 0; i < 4; i++)
#pragma unroll
          for (int j = 0; j < 4; j++)
#pragma unroll
            for (int r = 0; r < 4; r++) {
              int row = i * 16 + lq * 4 + r;    // 0..63 (c within pass)
              int col = wn * 64 + j * 16 + lr;  // 0..127 (n)
              tl[row * 136 + col] = f2bf(acc[i][j][r] + bv[cb + p * 64 + row]);
            }
      }
      __syncthreads();
      int row = t >> 2, q = t & 3;
      unsigned short* dst = &vbuf[((size_t)b * CC + cb + p * 64 + row) * NN + n0 + q * 32];
      const unsigned short* srcl = &tl[row * 136 + q * 32];
#pragma unroll
      for (int h = 0; h < 4; h++)
        *(bf16x8*)(&dst[h * 8]) = *(const bf16x8*)(&srcl[h * 8]);
    }
  }
}

// ---------------------------------------------------------------------------
// Kernel 3: flash (R12 body: V->LDS staged, coalesced Kp). THIS ROUND:
//   EPILOGUE coalesced — g*acc*invL goes through a [256][68] fp32 LDS tile
//   (aliased over the dead Vl+P region, no LDS growth) and the final
//   out = trans + x streams as float4 in 256B segments (was: 64+64 scalar
//   fp32 ops/thread in 64B segments at 2KB c-stride = half of flash's
//   traffic in scatter mode).
// ---------------------------------------------------------------------------
#define QT 64
#define MC 64
#define PSTR 72  // ushort units; 144B row stride

__global__ __launch_bounds__(256, 2) void k_flash(
    const unsigned short* __restrict__ Qb, const unsigned short* __restrict__ Kp,
    const unsigned short* __restrict__ vbuf,
    const float* __restrict__ x, const float* __restrict__ gamma,
    float* __restrict__ out) {
  __shared__ __align__(16) char smem[74752];  // union: Vl(64K)+P(9K) | trans(69.6K)
  __shared__ float red[4 * QT];               // 1024 B
  __shared__ float fin[QT];                   // 256 B
  unsigned short* Vl0 = (unsigned short*)smem;            // 256*64 ushorts
  unsigned short* Vl1 = (unsigned short*)(smem + 32768);  // 256*64 ushorts
  unsigned short* P = (unsigned short*)(smem + 65536);    // QT*PSTR ushorts
  float* trans = (float*)smem;                            // [256][68] floats

  // XCD-aware swizzle: hw block h -> logical id (h%8)*64 + h/8 (512 = 8*64).
  int bid = blockIdx.x;
  int swz = (bid & 7) * 64 + (bid >> 3);
  int ntile = swz & 15;
  int chalf = (swz >> 4) & 1;
  int b = swz >> 5;
  int n0 = ntile * QT;
  int t = threadIdx.x;
  int w = t >> 6, l = t & 63;
  int lr = l & 15, lq = l >> 4;
  const unsigned short* Qbb = Qb + (size_t)b * NN * 64;
  const unsigned short* Kpb = Kp + (size_t)b * 65536;
  const unsigned short* Vg = vbuf + ((size_t)b * CC + chalf * 256) * NN;

  // --- V staging constants (R11) ---
  int chb = t >> 3;                              // 0..31
  int koff = ((t & 7) * 8) ^ ((chb & 7) << 3);   // pre-swizzled global src
  int sbase = w * 512;                           // wave-uniform LDS lane-0 offset

  // Q fragments (constant over all chunks)
  bf16x8 aq[4][2];
#pragma unroll
  for (int nj = 0; nj < 4; nj++)
#pragma unroll
    for (int ks = 0; ks < 2; ks++)
      aq[nj][ks] = *(const bf16x8*)(&Qbb[(size_t)(n0 + nj * 16 + lr) * 64 + ks * 32 + lq * 8]);

  f32x4 acc[4][4];  // [ci][nj]
#pragma unroll
  for (int ci = 0; ci < 4; ci++)
#pragma unroll
    for (int nj = 0; nj < 4; nj++) acc[ci][nj] = (f32x4){0.f, 0.f, 0.f, 0.f};
  float sreg[4][4];
#pragma unroll
  for (int nj = 0; nj < 4; nj++)
#pragma unroll
    for (int r = 0; r < 4; r++) sreg[nj][r] = 0.f;

  // Prologue: stage V(chunk 0) into buf 0.
#pragma unroll
  for (int g = 0; g < 8; g++)
    gll16(&Vg[(size_t)(g * 32 + chb) * NN + koff], &Vl0[g * 2048 + sbase]);

  // Prologue: scores+exp for chunk 0 (Kp coalesced).
  float ev[4][4];
  {
    const unsigned short* kb = &Kpb[(size_t)w * 1024 + lr * 8];
    bf16x8 kf0 = *(const bf16x8*)(&kb[lq * 128]);
    bf16x8 kf1 = *(const bf16x8*)(&kb[(lq + 4) * 128]);
#pragma unroll
    for (int nj = 0; nj < 4; nj++) {
      f32x4 s = (f32x4){0.f, 0.f, 0.f, 0.f};
      s = __builtin_amdgcn_mfma_f32_16x16x32_bf16(aq[nj][0], kf0, s, 0, 0, 0);
      s = __builtin_amdgcn_mfma_f32_16x16x32_bf16(aq[nj][1], kf1, s, 0, 0, 0);
#pragma unroll
      for (int r = 0; r < 4; r++) {
        float e = __expf(s[r]);
        ev[nj][r] = e;
        sreg[nj][r] += e;
      }
    }
  }

  int cur = 0;
  for (int m0 = 0; m0 < NN; m0 += MC, cur ^= 1) {
    bool hn = (m0 + MC < NN);
    unsigned short* Vc = cur ? Vl1 : Vl0;
    unsigned short* Vn = cur ? Vl0 : Vl1;
    // Next-chunk K fragments (coalesced 2KB/wave; ride across barrier1).
    bf16x8 kf0n, kf1n;
    if (hn) {
      const unsigned short* kb = &Kpb[(size_t)(((m0 + MC) >> 4) + w) * 1024 + lr * 8];
      kf0n = *(const bf16x8*)(&kb[lq * 128]);
      kf1n = *(const bf16x8*)(&kb[(lq + 4) * 128]);
    }

    // barrier1: prev chunk's PV reads (P and Vn) complete.
    asm volatile("s_waitcnt lgkmcnt(0)" ::: "memory");
    __builtin_amdgcn_sched_barrier(0);
    __builtin_amdgcn_s_barrier();

    // Stage V(next chunk) into Vn.
    if (hn) {
#pragma unroll
      for (int g = 0; g < 8; g++)
        gll16(&Vg[(size_t)(g * 32 + chb) * NN + (m0 + MC) + koff], &Vn[g * 2048 + sbase]);
    }

    // P-write for this chunk.
#pragma unroll
    for (int nj = 0; nj < 4; nj++)
#pragma unroll
      for (int r = 0; r < 4; r++)
        P[(nj * 16 + lq * 4 + r) * PSTR + w * 16 + lr] = f2bf(ev[nj][r]);

    // Scores+exp for NEXT chunk while P settles.
    if (hn) {
#pragma unroll
      for (int nj = 0; nj < 4; nj++) {
        f32x4 s = (f32x4){0.f, 0.f, 0.f, 0.f};
        s = __builtin_amdgcn_mfma_f32_16x16x32_bf16(aq[nj][0], kf0n, s, 0, 0, 0);
        s = __builtin_amdgcn_mfma_f32_16x16x32_bf16(aq[nj][1], kf1n, s, 0, 0, 0);
#pragma unroll
        for (int r = 0; r < 4; r++) {
          float e = __expf(s[r]);
          ev[nj][r] = e;
          sreg[nj][r] += e;
        }
      }
    }

    // barrier2: P visible + Vc landed; next-chunk stage stays in flight.
    if (hn) {
      asm volatile("s_waitcnt vmcnt(8) lgkmcnt(0)" ::: "memory");
    } else {
      asm volatile("s_waitcnt vmcnt(0) lgkmcnt(0)" ::: "memory");
    }
    __builtin_amdgcn_sched_barrier(0);
    __builtin_amdgcn_s_barrier();

    // PV: V fragments from LDS (swizzled read), P fragments from LDS.
#pragma unroll
    for (int ks = 0; ks < 2; ks++) {
      bf16x8 vf[4];
#pragma unroll
      for (int ci = 0; ci < 4; ci++) {
        int row = w * 64 + ci * 16 + lr;
        int idx = row * 64 + (((ks * 32 + lq * 8)) ^ ((lr & 7) << 3));
        vf[ci] = *(const bf16x8*)(&Vc[idx]);
      }
#pragma unroll
      for (int nj = 0; nj < 4; nj++) {
        bf16x8 pf = *(const bf16x8*)(&P[(nj * 16 + lr) * PSTR + ks * 32 + lq * 8]);
#pragma unroll
        for (int ci = 0; ci < 4; ci++)
          acc[ci][nj] = __builtin_amdgcn_mfma_f32_16x16x32_bf16(vf[ci], pf, acc[ci][nj], 0, 0, 0);
      }
    }
  }

  // ---- final row sums (across 16 lr lanes, then 4 waves) ----
#pragma unroll
  for (int nj = 0; nj < 4; nj++)
#pragma unroll
    for (int r = 0; r < 4; r++) {
#pragma unroll
      for (int d = 1; d < 16; d <<= 1) sreg[nj][r] += __shfl_xor(sreg[nj][r], d, 64);
    }
  __syncthreads();  // also: all Vl/P reads done -> trans may overwrite below
  if (lr == 0) {
#pragma unroll
    for (int nj = 0; nj < 4; nj++)
#pragma unroll
      for (int r = 0; r < 4; r++) red[w * QT + nj * 16 + lq * 4 + r] = sreg[nj][r];
  }
  __syncthreads();
  if (t < QT) {
    float ssum = red[t] + red[QT + t] + red[2 * QT + t] + red[3 * QT + t];
    fin[t] = ssum;
  }
  __syncthreads();

  float invL[4];
#pragma unroll
  for (int nj = 0; nj < 4; nj++) invL[nj] = 1.0f / fin[nj * 16 + lr];
  float g = gamma[0];

  // ---- coalesced epilogue: normalized acc -> trans[256][68], then
  //      out = trans + x in 256B segments ----
#pragma unroll
  for (int ci = 0; ci < 4; ci++)
#pragma unroll
    for (int nj = 0; nj < 4; nj++)
#pragma unroll
      for (int r = 0; r < 4; r++) {
        int c_local = w * 64 + ci * 16 + lq * 4 + r;
        trans[c_local * 68 + nj * 16 + lr] = g * acc[ci][nj][r] * invL[nj];
      }
  __syncthreads();

  const float* xb = x + ((size_t)b * CC + chalf * 256) * NN + n0;
  float* ob = out + ((size_t)b * CC + chalf * 256) * NN + n0;
#pragma unroll
  for (int it = 0; it < 4; it++) {
    int unit = it * 256 + t;
    int row = unit >> 2, q = unit & 3;
#pragma unroll
    for (int v = 0; v < 4; v++) {
      float4 xv = *(const float4*)(&xb[(size_t)row * NN + q * 16 + v * 4]);
      float4 tv = *(const float4*)(&trans[row * 68 + q * 16 + v * 4]);
      float4 ov;
      ov.x = tv.x + xv.x; ov.y = tv.y + xv.y;
      ov.z = tv.z + xv.z; ov.w = tv.w + xv.w;
      *(float4*)(&ob[(size_t)row * NN + q * 16 + v * 4]) = ov;
    }
  }
}

// ---------------------------------------------------------------------------
extern "C" void kernel_launch(void* const* d_in, const int* in_sizes, int n_in,
                              void* d_out, int out_size, void* d_ws, size_t ws_size,
                              hipStream_t stream) {
  (void)in_sizes; (void)n_in; (void)out_size; (void)ws_size;
  const float* x     = (const float*)d_in[0];
  const float* Wq    = (const float*)d_in[1];
  const float* bq    = (const float*)d_in[2];
  const float* Wk    = (const float*)d_in[3];
  const float* bk    = (const float*)d_in[4];
  const float* Wv    = (const float*)d_in[5];
  const float* bv    = (const float*)d_in[6];
  const float* gamma = (const float*)d_in[7];
  float* out = (float*)d_out;

  char* ws = (char*)d_ws;
  unsigned short* Wall = (unsigned short*)(ws);                       // 655,360 B
  unsigned short* xT   = (unsigned short*)(ws + 655360);              // 16,777,216 B
  unsigned short* Qb   = (unsigned short*)(ws + 655360 + 16777216);   // 2,097,152 B
  unsigned short* Kp   = (unsigned short*)(ws + 655360 + 16777216 + 2097152);  // 2,097,152 B
  unsigned short* vbuf = (unsigned short*)(ws + 655360 + 16777216 + 2097152 + 2097152);  // 16,777,216 B
  // total ~38.4 MB

  k_prep<<<dim3(NN / 64, CC / 64, BB), dim3(256), 0, stream>>>(x, xT, Wq, Wk, Wv, Wall);
  k_gemm1<<<dim3(640), dim3(256), 0, stream>>>(Wall, xT, bq, bk, bv, Qb, Kp, vbuf);
  k_flash<<<dim3(512), dim3(256), 0, stream>>>(Qb, Kp, vbuf, x, gamma, out);
}